// Round 4
// baseline (9.779 us; speedup 1.0000x reference)
//
#include <hip/hip_runtime.h>

// QuantumLayer via bond-dim-2 transfer-matrix contraction (full-angle form),
// 4 samples per thread to amortize thread-uniform weight trig + deepen ILP.
//
// Math (validated R0-R2, passed absmax 3.9e-3):
// alpha_i = x_i + w0_i; ca=cos(alpha), sa=sin(alpha); cb=cos(w1), sb=sin(w1).
// Environment f (symmetric 2x2: f00, f11, u), site 0:
//   f00 = (1+ca)/2*cb, f11 = -(1-ca)/2*cb, u = -sa/2*sb
// site i>0:
//   S=(f00+f11)/2, D=(f00-f11)/2
//   f00 = cb*(S + ca*D + sa*u); f11 = -cb*(S - ca*D + sa*u); u = -sb*(sa*S + u)
// close: z_i = f00 + f11 + tail*2u, tail = sa[i+1] (1 for i=7).

__device__ __forceinline__ void contract_sample(
    const float xv[8], const float w0v[8],
    const float cb[8], const float sb[8],
    float z[8])
{
    float ca[8], sa[8];
#pragma unroll
    for (int i = 0; i < 8; ++i)
        __sincosf(xv[i] + w0v[i], &sa[i], &ca[i]);

    float f00 = 0.5f * (1.0f + ca[0]) * cb[0];
    float f11 = -0.5f * (1.0f - ca[0]) * cb[0];
    float u   = -0.5f * sa[0] * sb[0];

#pragma unroll
    for (int i = 0; i < 8; ++i) {
        if (i > 0) {
            float S = 0.5f * (f00 + f11);
            float D = 0.5f * (f00 - f11);
            float cD = ca[i] * D;
            float su = sa[i] * u;
            float h00 = (S + cD) + su;
            float h11 = (S - cD) + su;
            float h01 = fmaf(sa[i], S, u);
            f00 = cb[i] * h00;
            f11 = -cb[i] * h11;
            u   = -sb[i] * h01;
        }
        float tail = (i < 7) ? sa[i + 1] : 1.0f;
        z[i] = (f00 + f11) + tail * (u + u);
    }
}

__global__ __launch_bounds__(256) void qlayer_mps_kernel(
    const float* __restrict__ x,   // (B, 8)
    const float* __restrict__ w,   // (2, 8) flat: w0[0..7], w1[0..7]
    float* __restrict__ out,       // (B, 8)
    int quarter)                   // B/4
{
    int t = blockIdx.x * blockDim.x + threadIdx.x;
    if (t >= quarter) return;

    // uniform weights -> s_load; uniform trig computed once, shared by 4 samples
    const float4* w4 = reinterpret_cast<const float4*>(w);
    float4 w0lo = w4[0], w0hi = w4[1];
    float4 w1lo = w4[2], w1hi = w4[3];
    float w0v[8] = {w0lo.x, w0lo.y, w0lo.z, w0lo.w, w0hi.x, w0hi.y, w0hi.z, w0hi.w};
    float w1v[8] = {w1lo.x, w1lo.y, w1lo.z, w1lo.w, w1hi.x, w1hi.y, w1hi.z, w1hi.w};
    float cb[8], sb[8];
#pragma unroll
    for (int i = 0; i < 8; ++i)
        __sincosf(w1v[i], &sb[i], &cb[i]);

    // four samples: t + k*quarter, each a coalesced 2x float4 stream
    const float4* xbase = reinterpret_cast<const float4*>(x);
    float4* obase = reinterpret_cast<float4*>(out);

    float xs[4][8], zs[4][8];
#pragma unroll
    for (int k = 0; k < 4; ++k) {
        const float4* p = xbase + ((size_t)t + (size_t)k * quarter) * 2;
        float4 lo = p[0], hi = p[1];
        xs[k][0] = lo.x; xs[k][1] = lo.y; xs[k][2] = lo.z; xs[k][3] = lo.w;
        xs[k][4] = hi.x; xs[k][5] = hi.y; xs[k][6] = hi.z; xs[k][7] = hi.w;
    }

#pragma unroll
    for (int k = 0; k < 4; ++k)
        contract_sample(xs[k], w0v, cb, sb, zs[k]);

#pragma unroll
    for (int k = 0; k < 4; ++k) {
        float4* p = obase + ((size_t)t + (size_t)k * quarter) * 2;
        p[0] = make_float4(zs[k][0], zs[k][1], zs[k][2], zs[k][3]);
        p[1] = make_float4(zs[k][4], zs[k][5], zs[k][6], zs[k][7]);
    }
}

extern "C" void kernel_launch(void* const* d_in, const int* in_sizes, int n_in,
                              void* d_out, int out_size, void* d_ws, size_t ws_size,
                              hipStream_t stream) {
    const float* x = (const float*)d_in[0];
    const float* w = (const float*)d_in[1];
    float* out = (float*)d_out;
    int B = in_sizes[0] / 8;
    int quarter = B / 4;
    int threads = 256;
    int blocks = (quarter + threads - 1) / threads;
    hipLaunchKernelGGL(qlayer_mps_kernel, dim3(blocks), dim3(threads), 0, stream,
                       x, w, out, quarter);
}